// Round 1
// baseline (976.578 us; speedup 1.0000x reference)
//
#include <hip/hip_runtime.h>
#include <hip/hip_bf16.h>
#include <stdint.h>

#define NTOK 16384
#define DM   2048
#define NE   8
#define KTOT (2 * DM)   // pair-grouped: K = 4096
#define MAXT 160        // max m-tiles: 16384/128 + 28 pairs = 156; padded
#define NT   16         // 16 ntiles of 128 cols

typedef __bf16 bf16x8 __attribute__((ext_vector_type(8)));
typedef float f32x4 __attribute__((ext_vector_type(4)));
typedef unsigned short ushort_t;

typedef __attribute__((address_space(3))) void lds_void;
typedef __attribute__((address_space(1))) void g_void;
#define GLOAD_LDS16(g, l) \
  __builtin_amdgcn_global_load_lds((g_void*)(void*)(g), (lds_void*)(l), 16, 0, 0)

// RNE float -> bf16
__device__ __forceinline__ ushort_t f2bf(float f) {
  uint32_t u = __builtin_bit_cast(uint32_t, f);
  u = (u + 0x7FFFu + ((u >> 16) & 1u)) >> 16;
  return (ushort_t)u;
}

// ---------------- fused prep: W->bf16 convert (blocks 0..8191) + router (blocks 8192..12287) ----
__global__ void prep_kernel(const float* __restrict__ W, ushort_t* __restrict__ Wb,
                            const float* __restrict__ hs, const float* __restrict__ Wg,
                            const float* __restrict__ bg, int* __restrict__ pair_cnt,
                            int* __restrict__ pairs, ushort_t* __restrict__ hsb) {
  if (blockIdx.x < 8192) {
    // convert W: 8.39M float4 items, 4 per thread, wave-contiguous (coalesced)
    long i0 = (long)blockIdx.x * 1024 + threadIdx.x;
#pragma unroll
    for (int u = 0; u < 4; u++) {
      long i = i0 + u * 256;
      float4 v = ((const float4*)W)[i];
      ((ushort4*)Wb)[i] = make_ushort4(f2bf(v.x), f2bf(v.y), f2bf(v.z), f2bf(v.w));
    }
    return;
  }
  // router: one wave per token, fp64 accum; also emits hsb (bf16 hs, token order)
  int token = (((int)blockIdx.x - 8192) * 256 + (int)threadIdx.x) >> 6;
  int lane = threadIdx.x & 63;
  if (token >= NTOK) return;
  const float4* h4 = (const float4*)(hs + (size_t)token * DM);
  const float4* w4 = (const float4*)Wg;
  ushort4* o4 = (ushort4*)(hsb + (size_t)token * DM);
  double acc[NE] = {};
#pragma unroll
  for (int j = 0; j < 8; j++) {
    int c = lane + 64 * j;
    float4 h = h4[c];
    o4[c] = make_ushort4(f2bf(h.x), f2bf(h.y), f2bf(h.z), f2bf(h.w));
#pragma unroll
    for (int e = 0; e < NE; e++) {
      float4 w = w4[e * (DM / 4) + c];
      acc[e] += (double)h.x * w.x + (double)h.y * w.y + (double)h.z * w.z + (double)h.w * w.w;
    }
  }
#pragma unroll
  for (int off = 32; off > 0; off >>= 1)
#pragma unroll
    for (int e = 0; e < NE; e++) acc[e] += __shfl_down(acc[e], off, 64);
  if (lane == 0) {
    double lg[NE];
#pragma unroll
    for (int e = 0; e < NE; e++) lg[e] = acc[e] + (double)bg[e];
    int e1 = 0; double m1 = lg[0];
#pragma unroll
    for (int e = 1; e < NE; e++) if (lg[e] > m1) { m1 = lg[e]; e1 = e; }  // strict >: lower idx wins ties
    int e2 = -1; double m2 = -1e300;
#pragma unroll
    for (int e = 0; e < NE; e++) if (e != e1 && lg[e] > m2) { m2 = lg[e]; e2 = e; }
    int lo = min(e1, e2), hi = max(e1, e2);
    pairs[token] = lo * NE + hi;      // unordered pair id (order irrelevant: unweighted sum)
    atomicAdd(&pair_cnt[lo * NE + hi], 1);
  }
}

// ---------------- scan: one wave, shuffle prefix sums over 64 pair slots ----------------
__global__ void scan_kernel(const int* __restrict__ pair_cnt, int* __restrict__ meta,
                            int* __restrict__ pair_off, int* __restrict__ tile_pid,
                            int* __restrict__ tile_tokoff, int* __restrict__ tile_nrows) {
  int lane = threadIdx.x;   // 64 threads = 1 wave
  int c = pair_cnt[lane];
  int off = c;
#pragma unroll
  for (int d = 1; d < 64; d <<= 1) { int t = __shfl_up(off, d, 64); if (lane >= d) off += t; }
  off -= c;
  pair_off[lane] = off;
  int nt = (c + 127) >> 7;
  int toff = nt;
#pragma unroll
  for (int d = 1; d < 64; d <<= 1) { int t = __shfl_up(toff, d, 64); if (lane >= d) toff += t; }
  toff -= nt;
  for (int m = 0; m < nt; m++) {
    tile_pid[toff + m] = lane;
    tile_tokoff[toff + m] = off + m * 128;
    tile_nrows[toff + m] = min(c - m * 128, 128);
  }
  if (lane == 63) meta[0] = toff + nt;
}

// ---------------- scatter tokens into pair-group lists ----------------
__global__ void scatter_kernel(const int* __restrict__ pairs, const int* __restrict__ pair_off,
                               int* __restrict__ pair_fill, int* __restrict__ token_list) {
  int t = blockIdx.x * blockDim.x + threadIdx.x;
  if (t >= NTOK) return;
  int pid = pairs[t];
  int pos = atomicAdd(&pair_fill[pid], 1);
  token_list[pair_off[pid] + pos] = t;
}

// ---------------- grouped GEMM over expert pairs ----------------
// Block tile 128(tokens) x 128(cols), K = 4096 (W[e1] then W[e2]; A = [hs|hs]), BK = 64.
// 256 threads = 4 waves arranged 2(m) x 2(n); each wave owns a 64x64 quadrant (4x4 mfma
// 16x16x32). Fragment-major LDS: chunk = one 16x32 MFMA tile = 1 KB in lane order
// (lane L's 16B at chunk + L*16). A: 16 chunks (8 mtiles x 2 kk); B: 16 chunks
// (8 ntiles x 2 kk). Wave w stages A chunks {4w..4w+3} (mi = 2w,2w+1 x kk) and B chunks
// {4w..4w+3} (ni = 2w,2w+1 x kk). All ds_read_b128 at base+lane*16: conflict-free.
// LDS = exactly 32 KB (token ids kept in registers, not LDS) -> 4 blocks/CU co-resident
// at the 16-wave/CU register ceiling (116 unified regs/wave): 4 independent vmcnt-stall
// domains per CU instead of 2.
__global__ __launch_bounds__(256, 4) void moe_gemm(
    const ushort_t* __restrict__ hsb, const ushort_t* __restrict__ Wb,
    const float* __restrict__ bias, const int* __restrict__ token_list,
    const int* __restrict__ meta, const int* __restrict__ tile_pid,
    const int* __restrict__ tile_tokoff, const int* __restrict__ tile_nrows,
    float* __restrict__ out)
{
  __shared__ ushort_t Als[16 * 512];   // 16 KB
  __shared__ ushort_t Bls[16 * 512];   // 16 KB

  const int ntile = blockIdx.x & (NT - 1);
  const int btile = blockIdx.x >> 4;
  if (btile >= meta[0]) return;
  const int pid = tile_pid[btile];
  const int e1 = pid >> 3, e2 = pid & 7;
  const int tokoff = tile_tokoff[btile];
  const int nrows = tile_nrows[btile];
  const int n0 = ntile * 128;

  const int tid = threadIdx.x;
  const int lane = tid & 63;
  const int wave = tid >> 6;      // 0..3
  const int l15 = lane & 15;
  const int lhi = lane >> 4;      // 0..3

  // A staging token rows for this wave: mi = 2*wave (r0), 2*wave+1 (r1)
  const int r0 = wave * 32 + l15;
  const int r1 = r0 + 16;
  const int t0 = (r0 < nrows) ? token_list[tokoff + r0] : 0;  // pad rows -> row 0
  const int t1 = (r1 < nrows) ? token_list[tokoff + r1] : 0;
  const ushort_t* arow0 = hsb + (size_t)t0 * DM + lhi * 8;
  const ushort_t* arow1 = hsb + (size_t)t1 * DM + lhi * 8;
  const size_t brow0 = (size_t)(n0 + wave * 32 + l15) * DM + lhi * 8;  // ni = 2w
  const size_t brow1 = brow0 + (size_t)16 * DM;                        // ni = 2w+1
  ushort_t* als = Als + wave * 2048;   // chunks 4w..4w+3
  ushort_t* bls = Bls + wave * 2048;   // chunks 4w..4w+3

  f32x4 acc[4][4] = {};
  const size_t wstride = (size_t)DM * DM;
  const int miB = (wave >> 1) * 4;     // m-subtile base for compute
  const int niB = (wave & 1) * 4;      // n-subtile base for compute

  for (int k0 = 0; k0 < KTOT; k0 += 64) {
    const int ka = k0 & (DM - 1);      // A and B k-offsets both wrap at DM
    const ushort_t* wbase = Wb + (size_t)(k0 < DM ? e1 : e2) * wstride + ka;
    GLOAD_LDS16(arow0 + ka,         als);
    GLOAD_LDS16(arow0 + ka + 32,    als + 512);
    GLOAD_LDS16(arow1 + ka,         als + 1024);
    GLOAD_LDS16(arow1 + ka + 32,    als + 1536);
    GLOAD_LDS16(wbase + brow0,      bls);
    GLOAD_LDS16(wbase + brow0 + 32, bls + 512);
    GLOAD_LDS16(wbase + brow1,      bls + 1024);
    GLOAD_LDS16(wbase + brow1 + 32, bls + 1536);
    __syncthreads();
#pragma unroll
    for (int kk = 0; kk < 2; kk++) {
      bf16x8 af[4], bfr[4];
#pragma unroll
      for (int i = 0; i < 4; i++)
        af[i] = *(const bf16x8*)(&Als[((miB + i) * 2 + kk) * 512 + lane * 8]);
#pragma unroll
      for (int j = 0; j < 4; j++)
        bfr[j] = *(const bf16x8*)(&Bls[((niB + j) * 2 + kk) * 512 + lane * 8]);
#pragma unroll
      for (int i = 0; i < 4; i++)
#pragma unroll
        for (int j = 0; j < 4; j++)
          acc[i][j] = __builtin_amdgcn_mfma_f32_16x16x32_bf16(af[i], bfr[j], acc[i][j], 0, 0, 0);
    }
    __syncthreads();
  }

  // epilogue: C/D layout col=lane&15, row=(lane>>4)*4+reg; one writer per element
  const int wm = (wave >> 1) * 64;
  const int wn = (wave & 1) * 64;
  int tokr[4][4];
#pragma unroll
  for (int i = 0; i < 4; i++)
#pragma unroll
    for (int r = 0; r < 4; r++) {
      const int row = wm + i * 16 + lhi * 4 + r;
      tokr[i][r] = (row < nrows) ? token_list[tokoff + row] : -1;
    }
#pragma unroll
  for (int j = 0; j < 4; j++) {
    const int col = n0 + wn + j * 16 + l15;
    const float bsum = bias[e1 * DM + col] + bias[e2 * DM + col];
#pragma unroll
    for (int i = 0; i < 4; i++)
#pragma unroll
      for (int r = 0; r < 4; r++) {
        const int tok = tokr[i][r];
        if (tok >= 0) out[(size_t)tok * DM + col] = acc[i][j][r] + bsum;
      }
  }
}

extern "C" void kernel_launch(void* const* d_in, const int* in_sizes, int n_in,
                              void* d_out, int out_size, void* d_ws, size_t ws_size,
                              hipStream_t stream) {
  const float* hs = (const float*)d_in[0];
  const float* Wg = (const float*)d_in[1];
  const float* bg = (const float*)d_in[2];
  const float* W  = (const float*)d_in[3];
  const float* b  = (const float*)d_in[4];
  float* out = (float*)d_out;

  char* ws = (char*)d_ws;
  int* pair_cnt    = (int*)(ws + 0);      // 64 ints
  int* pair_fill   = (int*)(ws + 256);    // 64 ints
  int* meta        = (int*)(ws + 512);    // 16 ints
  int* pair_off    = (int*)(ws + 576);    // 64 ints
  int* tile_pid    = (int*)(ws + 832);    // MAXT
  int* tile_tokoff = (int*)(ws + 1600);   // MAXT
  int* tile_nrows  = (int*)(ws + 2368);   // MAXT
  int* pairs       = (int*)(ws + 3136);   // 16384
  int* token_list  = (int*)(ws + 68672);  // 16384
  ushort_t* Wb  = (ushort_t*)(ws + 134400);              // 64 MiB
  ushort_t* hsb = (ushort_t*)(ws + 134400 + 67108864);   // 64 MiB

  hipMemsetAsync(d_ws, 0, 576, stream);   // pair_cnt + pair_fill + meta

  prep_kernel<<<8192 + 4096, 256, 0, stream>>>(W, Wb, hs, Wg, bg, pair_cnt, pairs, hsb);
  scan_kernel<<<1, 64, 0, stream>>>(pair_cnt, meta, pair_off, tile_pid, tile_tokoff, tile_nrows);
  scatter_kernel<<<NTOK / 256, 256, 0, stream>>>(pairs, pair_off, pair_fill, token_list);
  moe_gemm<<<MAXT * NT, 256, 0, stream>>>(hsb, Wb, b, token_list, meta,
                                          tile_pid, tile_tokoff, tile_nrows, out);
}

// Round 2
// 887.697 us; speedup vs baseline: 1.1001x; 1.1001x over previous
//
#include <hip/hip_runtime.h>
#include <hip/hip_bf16.h>
#include <stdint.h>

#define NTOK 16384
#define DM   2048
#define NE   8
#define MAXT 160        // ws layout capacity for tile arrays (96 used)
#define MAXB 96         // max m-tiles at 256 rows: sum ceil(c_p/256) <= 64+27=91; padded
#define NT   8          // 8 ntiles of 256 cols

typedef __bf16 bf16x8 __attribute__((ext_vector_type(8)));
typedef float f32x4 __attribute__((ext_vector_type(4)));
typedef unsigned short ushort_t;

typedef __attribute__((address_space(3))) void lds_void;
typedef __attribute__((address_space(1))) void g_void;
#define GLOAD_LDS16(g, l) \
  __builtin_amdgcn_global_load_lds((g_void*)(void*)(g), (lds_void*)(l), 16, 0, 0)

// RNE float -> bf16
__device__ __forceinline__ ushort_t f2bf(float f) {
  uint32_t u = __builtin_bit_cast(uint32_t, f);
  u = (u + 0x7FFFu + ((u >> 16) & 1u)) >> 16;
  return (ushort_t)u;
}

// ---------------- fused prep: W->bf16 convert (blocks 0..8191) + router (blocks 8192..12287) ----
__global__ void prep_kernel(const float* __restrict__ W, ushort_t* __restrict__ Wb,
                            const float* __restrict__ hs, const float* __restrict__ Wg,
                            const float* __restrict__ bg, int* __restrict__ pair_cnt,
                            int* __restrict__ pairs, ushort_t* __restrict__ hsb) {
  if (blockIdx.x < 8192) {
    // convert W: 8.39M float4 items, 4 per thread, wave-contiguous (coalesced)
    long i0 = (long)blockIdx.x * 1024 + threadIdx.x;
#pragma unroll
    for (int u = 0; u < 4; u++) {
      long i = i0 + u * 256;
      float4 v = ((const float4*)W)[i];
      ((ushort4*)Wb)[i] = make_ushort4(f2bf(v.x), f2bf(v.y), f2bf(v.z), f2bf(v.w));
    }
    return;
  }
  // router: one wave per token, fp64 accum; also emits hsb (bf16 hs, token order)
  int token = (((int)blockIdx.x - 8192) * 256 + (int)threadIdx.x) >> 6;
  int lane = threadIdx.x & 63;
  if (token >= NTOK) return;
  const float4* h4 = (const float4*)(hs + (size_t)token * DM);
  const float4* w4 = (const float4*)Wg;
  ushort4* o4 = (ushort4*)(hsb + (size_t)token * DM);
  double acc[NE] = {};
#pragma unroll
  for (int j = 0; j < 8; j++) {
    int c = lane + 64 * j;
    float4 h = h4[c];
    o4[c] = make_ushort4(f2bf(h.x), f2bf(h.y), f2bf(h.z), f2bf(h.w));
#pragma unroll
    for (int e = 0; e < NE; e++) {
      float4 w = w4[e * (DM / 4) + c];
      acc[e] += (double)h.x * w.x + (double)h.y * w.y + (double)h.z * w.z + (double)h.w * w.w;
    }
  }
#pragma unroll
  for (int off = 32; off > 0; off >>= 1)
#pragma unroll
    for (int e = 0; e < NE; e++) acc[e] += __shfl_down(acc[e], off, 64);
  if (lane == 0) {
    double lg[NE];
#pragma unroll
    for (int e = 0; e < NE; e++) lg[e] = acc[e] + (double)bg[e];
    int e1 = 0; double m1 = lg[0];
#pragma unroll
    for (int e = 1; e < NE; e++) if (lg[e] > m1) { m1 = lg[e]; e1 = e; }  // strict >: lower idx wins ties
    int e2 = -1; double m2 = -1e300;
#pragma unroll
    for (int e = 0; e < NE; e++) if (e != e1 && lg[e] > m2) { m2 = lg[e]; e2 = e; }
    int lo = min(e1, e2), hi = max(e1, e2);
    pairs[token] = lo * NE + hi;      // unordered pair id (order irrelevant: unweighted sum)
    atomicAdd(&pair_cnt[lo * NE + hi], 1);
  }
}

// ---------------- scan: one wave, shuffle prefix sums over 64 pair slots ----------------
// 256-row tiles now.
__global__ void scan_kernel(const int* __restrict__ pair_cnt, int* __restrict__ meta,
                            int* __restrict__ pair_off, int* __restrict__ tile_pid,
                            int* __restrict__ tile_tokoff, int* __restrict__ tile_nrows) {
  int lane = threadIdx.x;   // 64 threads = 1 wave
  int c = pair_cnt[lane];
  int off = c;
#pragma unroll
  for (int d = 1; d < 64; d <<= 1) { int t = __shfl_up(off, d, 64); if (lane >= d) off += t; }
  off -= c;
  pair_off[lane] = off;
  int nt = (c + 255) >> 8;
  int toff = nt;
#pragma unroll
  for (int d = 1; d < 64; d <<= 1) { int t = __shfl_up(toff, d, 64); if (lane >= d) toff += t; }
  toff -= nt;
  for (int m = 0; m < nt; m++) {
    tile_pid[toff + m] = lane;
    tile_tokoff[toff + m] = off + m * 256;
    tile_nrows[toff + m] = min(c - m * 256, 256);
  }
  if (lane == 63) meta[0] = toff + nt;
}

// ---------------- scatter tokens into pair-group lists ----------------
__global__ void scatter_kernel(const int* __restrict__ pairs, const int* __restrict__ pair_off,
                               int* __restrict__ pair_fill, int* __restrict__ token_list) {
  int t = blockIdx.x * blockDim.x + threadIdx.x;
  if (t >= NTOK) return;
  int pid = pairs[t];
  int pos = atomicAdd(&pair_fill[pid], 1);
  token_list[pair_off[pid] + pos] = t;
}

// ---------------- grouped GEMM over expert pairs ----------------
// Block tile 256(tokens) x 256(cols), dual-expert: out = hs @ (W[e1]+W[e2])^T, so both
// experts' MFMAs accumulate into the SAME acc and each A-stage feeds 2x the compute.
// K = 2048, BK = 32. 512 threads = 8 waves arranged 2(m) x 4(n); each wave owns a
// 128x64 quadrant (8x4 mfma 16x16x32). Fragment-major LDS: chunk = one 16x32 MFMA tile
// = 1 KB in lane order (lane L's 16B at chunk + L*16); all ds_read_b128 at base+lane*16:
// conflict-free (measured 0). A: 16 chunks/buf (16 mtiles); B: 32 chunks/buf
// (2 experts x 16 ntiles). Double-buffered (96 KB total), min-2-phase: stage K+1 BEFORE
// computing K; single __syncthreads per K-step (its implicit vmcnt(0) lands the
// prefetch, which has had the whole 64-MFMA compute phase to fly).
// Grid 96x8, ntile = blockIdx.x & 7: XCD round-robin (%8) gives each XCD one 256-col
// slice -> its B working set (few experts x 1 MB) is L2-resident.
__global__ __launch_bounds__(512, 2) void moe_gemm(
    const ushort_t* __restrict__ hsb, const ushort_t* __restrict__ Wb,
    const float* __restrict__ bias, const int* __restrict__ token_list,
    const int* __restrict__ meta, const int* __restrict__ tile_pid,
    const int* __restrict__ tile_tokoff, const int* __restrict__ tile_nrows,
    float* __restrict__ out)
{
  __shared__ ushort_t Als[2 * 16 * 512];   // 32 KB (2 bufs x 16 chunks)
  __shared__ ushort_t Bls[2 * 32 * 512];   // 64 KB (2 bufs x 2 experts x 16 chunks)

  const int ntile = blockIdx.x & (NT - 1);   // == XCD id under %8 round-robin
  const int btile = blockIdx.x >> 3;         // consecutive in time per XCD, pid-sorted
  if (btile >= meta[0]) return;
  const int pid = tile_pid[btile];
  const int e1 = pid >> 3, e2 = pid & 7;
  const int tokoff = tile_tokoff[btile];
  const int nrows = tile_nrows[btile];
  const int n0 = ntile * 256;

  const int tid = threadIdx.x;
  const int lane = tid & 63;
  const int wave = tid >> 6;      // 0..7
  const int l15 = lane & 15;
  const int lhi = lane >> 4;      // 0..3

  // A staging rows for this wave: mtiles 2w (r0), 2w+1 (r1)
  const int r0 = wave * 32 + l15;
  const int r1 = r0 + 16;
  const int t0 = (r0 < nrows) ? token_list[tokoff + r0] : 0;  // pad rows -> row 0
  const int t1 = (r1 < nrows) ? token_list[tokoff + r1] : 0;
  const ushort_t* arow0 = hsb + (size_t)t0 * DM + lhi * 8;
  const ushort_t* arow1 = hsb + (size_t)t1 * DM + lhi * 8;
  // B staging rows: ntile16 2w (c0), 2w+1 (c0+16), for both experts
  const size_t wstride = (size_t)DM * DM;
  const size_t browc = (size_t)(n0 + wave * 32 + l15) * DM + lhi * 8;
  const ushort_t* b1row0 = Wb + (size_t)e1 * wstride + browc;
  const ushort_t* b1row1 = b1row0 + (size_t)16 * DM;
  const ushort_t* b2row0 = Wb + (size_t)e2 * wstride + browc;
  const ushort_t* b2row1 = b2row0 + (size_t)16 * DM;

  f32x4 acc[8][4] = {};
  const int miB = (wave >> 2) * 8;     // m-subtile base for compute (8 mtiles)
  const int niB = (wave & 3) * 4;      // n-subtile base for compute (4 ntiles)

#define STAGE(buf, ka)                                                        \
  { ushort_t* als = Als + (buf) * 8192 + wave * 1024;                         \
    ushort_t* bls = Bls + (buf) * 16384 + wave * 1024;                        \
    GLOAD_LDS16(arow0 + (ka),  als);                                          \
    GLOAD_LDS16(arow1 + (ka),  als + 512);                                    \
    GLOAD_LDS16(b1row0 + (ka), bls);                                          \
    GLOAD_LDS16(b1row1 + (ka), bls + 512);                                    \
    GLOAD_LDS16(b2row0 + (ka), bls + 8192);                                   \
    GLOAD_LDS16(b2row1 + (ka), bls + 8704); }

#define COMPUTE(buf)                                                          \
  { bf16x8 af[8];                                                             \
    _Pragma("unroll") for (int i = 0; i < 8; i++)                             \
      af[i] = *(const bf16x8*)(&Als[(buf) * 8192 + (miB + i) * 512 + lane * 8]); \
    _Pragma("unroll") for (int e = 0; e < 2; e++) {                           \
      bf16x8 bfr[4];                                                          \
      _Pragma("unroll") for (int j = 0; j < 4; j++)                           \
        bfr[j] = *(const bf16x8*)(&Bls[(buf) * 16384 + e * 8192 + (niB + j) * 512 + lane * 8]); \
      _Pragma("unroll") for (int i = 0; i < 8; i++)                           \
        _Pragma("unroll") for (int j = 0; j < 4; j++)                         \
          acc[i][j] = __builtin_amdgcn_mfma_f32_16x16x32_bf16(af[i], bfr[j], acc[i][j], 0, 0, 0); } }

  STAGE(0, 0);
  __syncthreads();
  int cur = 0;
  for (int k0 = 32; k0 < DM; k0 += 32) {
    STAGE(cur ^ 1, k0);    // prefetch next K-slice (flies during compute)
    COMPUTE(cur);
    __syncthreads();       // implicit vmcnt(0)+lgkmcnt(0): prefetch landed, reads done
    cur ^= 1;
  }
  COMPUTE(cur);

  // epilogue: C/D layout col=lane&15, row=(lane>>4)*4+reg; one writer per element
  const int wm = (wave >> 2) * 128;
  const int wn = (wave & 3) * 64;
  float bsum[4]; int colv[4];
#pragma unroll
  for (int j = 0; j < 4; j++) {
    colv[j] = n0 + wn + j * 16 + l15;
    bsum[j] = bias[e1 * DM + colv[j]] + bias[e2 * DM + colv[j]];
  }
#pragma unroll
  for (int i = 0; i < 8; i++) {
    int tokr[4];
#pragma unroll
    for (int r = 0; r < 4; r++) {
      const int row = wm + i * 16 + lhi * 4 + r;
      tokr[r] = (row < nrows) ? token_list[tokoff + row] : -1;
    }
#pragma unroll
    for (int j = 0; j < 4; j++)
#pragma unroll
      for (int r = 0; r < 4; r++)
        if (tokr[r] >= 0) out[(size_t)tokr[r] * DM + colv[j]] = acc[i][j][r] + bsum[j];
  }
#undef STAGE
#undef COMPUTE
}

extern "C" void kernel_launch(void* const* d_in, const int* in_sizes, int n_in,
                              void* d_out, int out_size, void* d_ws, size_t ws_size,
                              hipStream_t stream) {
  const float* hs = (const float*)d_in[0];
  const float* Wg = (const float*)d_in[1];
  const float* bg = (const float*)d_in[2];
  const float* W  = (const float*)d_in[3];
  const float* b  = (const float*)d_in[4];
  float* out = (float*)d_out;

  char* ws = (char*)d_ws;
  int* pair_cnt    = (int*)(ws + 0);      // 64 ints
  int* pair_fill   = (int*)(ws + 256);    // 64 ints
  int* meta        = (int*)(ws + 512);    // 16 ints
  int* pair_off    = (int*)(ws + 576);    // 64 ints
  int* tile_pid    = (int*)(ws + 832);    // MAXT capacity, 96 used
  int* tile_tokoff = (int*)(ws + 1600);   // MAXT
  int* tile_nrows  = (int*)(ws + 2368);   // MAXT
  int* pairs       = (int*)(ws + 3136);   // 16384
  int* token_list  = (int*)(ws + 68672);  // 16384
  ushort_t* Wb  = (ushort_t*)(ws + 134400);              // 64 MiB
  ushort_t* hsb = (ushort_t*)(ws + 134400 + 67108864);   // 64 MiB

  hipMemsetAsync(d_ws, 0, 576, stream);   // pair_cnt + pair_fill + meta

  prep_kernel<<<8192 + 4096, 256, 0, stream>>>(W, Wb, hs, Wg, bg, pair_cnt, pairs, hsb);
  scan_kernel<<<1, 64, 0, stream>>>(pair_cnt, meta, pair_off, tile_pid, tile_tokoff, tile_nrows);
  scatter_kernel<<<NTOK / 256, 256, 0, stream>>>(pairs, pair_off, pair_fill, token_list);
  moe_gemm<<<MAXB * NT, 512, 0, stream>>>(hsb, Wb, b, token_list, meta,
                                          tile_pid, tile_tokoff, tile_nrows, out);
}

// Round 3
// 840.825 us; speedup vs baseline: 1.1615x; 1.0557x over previous
//
#include <hip/hip_runtime.h>
#include <hip/hip_bf16.h>
#include <stdint.h>

#define NTOK 16384
#define DM   2048
#define NE   8
#define MAXT 160        // ws layout capacity for tile arrays (96 used)
#define MAXB 96         // max m-tiles at 256 rows: sum ceil(c_p/256) <= 64+27=91; padded
#define NT   8          // 8 ntiles of 256 cols

typedef __bf16 bf16x8 __attribute__((ext_vector_type(8)));
typedef float f32x4 __attribute__((ext_vector_type(4)));
typedef unsigned short ushort_t;

typedef __attribute__((address_space(3))) void lds_void;
typedef __attribute__((address_space(1))) void g_void;
#define GLOAD_LDS16(g, l) \
  __builtin_amdgcn_global_load_lds((g_void*)(void*)(g), (lds_void*)(l), 16, 0, 0)

// RNE float -> bf16
__device__ __forceinline__ ushort_t f2bf(float f) {
  uint32_t u = __builtin_bit_cast(uint32_t, f);
  u = (u + 0x7FFFu + ((u >> 16) & 1u)) >> 16;
  return (ushort_t)u;
}

// ---------------- fused prep: W->bf16 convert (blocks 0..8191) + router (blocks 8192..12287) ----
__global__ void prep_kernel(const float* __restrict__ W, ushort_t* __restrict__ Wb,
                            const float* __restrict__ hs, const float* __restrict__ Wg,
                            const float* __restrict__ bg, int* __restrict__ pair_cnt,
                            int* __restrict__ pairs, ushort_t* __restrict__ hsb) {
  if (blockIdx.x < 8192) {
    // convert W: 8.39M float4 items, 4 per thread, wave-contiguous (coalesced)
    long i0 = (long)blockIdx.x * 1024 + threadIdx.x;
#pragma unroll
    for (int u = 0; u < 4; u++) {
      long i = i0 + u * 256;
      float4 v = ((const float4*)W)[i];
      ((ushort4*)Wb)[i] = make_ushort4(f2bf(v.x), f2bf(v.y), f2bf(v.z), f2bf(v.w));
    }
    return;
  }
  // router: one wave per token, fp64 accum; also emits hsb (bf16 hs, token order)
  int token = (((int)blockIdx.x - 8192) * 256 + (int)threadIdx.x) >> 6;
  int lane = threadIdx.x & 63;
  if (token >= NTOK) return;
  const float4* h4 = (const float4*)(hs + (size_t)token * DM);
  const float4* w4 = (const float4*)Wg;
  ushort4* o4 = (ushort4*)(hsb + (size_t)token * DM);
  double acc[NE] = {};
#pragma unroll
  for (int j = 0; j < 8; j++) {
    int c = lane + 64 * j;
    float4 h = h4[c];
    o4[c] = make_ushort4(f2bf(h.x), f2bf(h.y), f2bf(h.z), f2bf(h.w));
#pragma unroll
    for (int e = 0; e < NE; e++) {
      float4 w = w4[e * (DM / 4) + c];
      acc[e] += (double)h.x * w.x + (double)h.y * w.y + (double)h.z * w.z + (double)h.w * w.w;
    }
  }
#pragma unroll
  for (int off = 32; off > 0; off >>= 1)
#pragma unroll
    for (int e = 0; e < NE; e++) acc[e] += __shfl_down(acc[e], off, 64);
  if (lane == 0) {
    double lg[NE];
#pragma unroll
    for (int e = 0; e < NE; e++) lg[e] = acc[e] + (double)bg[e];
    int e1 = 0; double m1 = lg[0];
#pragma unroll
    for (int e = 1; e < NE; e++) if (lg[e] > m1) { m1 = lg[e]; e1 = e; }  // strict >: lower idx wins ties
    int e2 = -1; double m2 = -1e300;
#pragma unroll
    for (int e = 0; e < NE; e++) if (e != e1 && lg[e] > m2) { m2 = lg[e]; e2 = e; }
    int lo = min(e1, e2), hi = max(e1, e2);
    pairs[token] = lo * NE + hi;      // unordered pair id (order irrelevant: unweighted sum)
    atomicAdd(&pair_cnt[lo * NE + hi], 1);
  }
}

// ---------------- scan: one wave, shuffle prefix sums over 64 pair slots ----------------
// 256-row tiles.
__global__ void scan_kernel(const int* __restrict__ pair_cnt, int* __restrict__ meta,
                            int* __restrict__ pair_off, int* __restrict__ tile_pid,
                            int* __restrict__ tile_tokoff, int* __restrict__ tile_nrows) {
  int lane = threadIdx.x;   // 64 threads = 1 wave
  int c = pair_cnt[lane];
  int off = c;
#pragma unroll
  for (int d = 1; d < 64; d <<= 1) { int t = __shfl_up(off, d, 64); if (lane >= d) off += t; }
  off -= c;
  pair_off[lane] = off;
  int nt = (c + 255) >> 8;
  int toff = nt;
#pragma unroll
  for (int d = 1; d < 64; d <<= 1) { int t = __shfl_up(toff, d, 64); if (lane >= d) toff += t; }
  toff -= nt;
  for (int m = 0; m < nt; m++) {
    tile_pid[toff + m] = lane;
    tile_tokoff[toff + m] = off + m * 256;
    tile_nrows[toff + m] = min(c - m * 256, 256);
  }
  if (lane == 63) meta[0] = toff + nt;
}

// ---------------- scatter tokens into pair-group lists ----------------
__global__ void scatter_kernel(const int* __restrict__ pairs, const int* __restrict__ pair_off,
                               int* __restrict__ pair_fill, int* __restrict__ token_list) {
  int t = blockIdx.x * blockDim.x + threadIdx.x;
  if (t >= NTOK) return;
  int pid = pairs[t];
  int pos = atomicAdd(&pair_fill[pid], 1);
  token_list[pair_off[pid] + pos] = t;
}

// ---------------- grouped GEMM over expert pairs ----------------
// Block tile 256(tokens) x 256(cols), dual-expert: out = hs @ (W[e1]+W[e2])^T; both
// experts' MFMAs accumulate into the SAME acc. K = 2048, BK = 32 slices (64 total).
// 512 threads = 8 waves 2(m) x 4(n); each wave owns 128x64 (8x4 mfma 16x16x32, x2 experts
// = 64 MFMA/step). Fragment-major LDS: chunk = one 16x32 MFMA tile = 1 KB in lane order
// (lane L's 16B at chunk + L*16); all ds_read_b128 at base+lane*16: conflict-free
// (measured 0). Per slice: A 16 chunks (16 KB) + B 32 chunks (2 experts x 16 ntiles,
// 32 KB). TRIPLE buffered (144 KB), prefetch depth 2: 6 gload_lds per wave per slice.
// Counted-vmcnt pipeline (T4): entering step t, slices t,t+1 outstanding (12 VMEM) ->
// s_waitcnt vmcnt(6) proves slice t landed; raw s_barrier makes all waves' writes
// visible AND frees buffer (t+2)%3 (read at t-1) for the stage issued after it.
// No vmcnt(0) in the main loop. setprio(1) around the MFMA cluster (T5).
// Grid 96x8, ntile = blockIdx.x & 7 = XCD id (%8 round-robin): each XCD owns one
// 256-col slice -> B working set L2/LLC-warm.
__global__ __launch_bounds__(512, 2) void moe_gemm(
    const ushort_t* __restrict__ hsb, const ushort_t* __restrict__ Wb,
    const float* __restrict__ bias, const int* __restrict__ token_list,
    const int* __restrict__ meta, const int* __restrict__ tile_pid,
    const int* __restrict__ tile_tokoff, const int* __restrict__ tile_nrows,
    float* __restrict__ out)
{
  __shared__ ushort_t Als[3 * 16 * 512];   // 48 KB (3 bufs x 16 chunks)
  __shared__ ushort_t Bls[3 * 32 * 512];   // 96 KB (3 bufs x 2 experts x 16 chunks)

  const int ntile = blockIdx.x & (NT - 1);   // == XCD id under %8 round-robin
  const int btile = blockIdx.x >> 3;
  if (btile >= meta[0]) return;
  const int pid = tile_pid[btile];
  const int e1 = pid >> 3, e2 = pid & 7;
  const int tokoff = tile_tokoff[btile];
  const int nrows = tile_nrows[btile];
  const int n0 = ntile * 256;

  const int tid = threadIdx.x;
  const int lane = tid & 63;
  const int wave = tid >> 6;      // 0..7
  const int l15 = lane & 15;
  const int lhi = lane >> 4;      // 0..3

  // A staging rows for this wave: mtiles 2w (r0), 2w+1 (r1)
  const int r0 = wave * 32 + l15;
  const int r1 = r0 + 16;
  const int t0 = (r0 < nrows) ? token_list[tokoff + r0] : 0;  // pad rows -> row 0
  const int t1 = (r1 < nrows) ? token_list[tokoff + r1] : 0;
  const ushort_t* arow0 = hsb + (size_t)t0 * DM + lhi * 8;
  const ushort_t* arow1 = hsb + (size_t)t1 * DM + lhi * 8;
  // B staging rows: ntile16 2w, 2w+1, both experts
  const size_t wstride = (size_t)DM * DM;
  const size_t browc = (size_t)(n0 + wave * 32 + l15) * DM + lhi * 8;
  const ushort_t* b1row0 = Wb + (size_t)e1 * wstride + browc;
  const ushort_t* b1row1 = b1row0 + (size_t)16 * DM;
  const ushort_t* b2row0 = Wb + (size_t)e2 * wstride + browc;
  const ushort_t* b2row1 = b2row0 + (size_t)16 * DM;

  f32x4 acc[8][4] = {};
  const int miB = (wave >> 2) * 8;     // m-subtile base for compute (8 mtiles)
  const int niB = (wave & 3) * 4;      // n-subtile base for compute (4 ntiles)

#define STAGE(buf, ka)                                                        \
  { ushort_t* als = Als + (buf) * 8192 + wave * 1024;                         \
    ushort_t* bls = Bls + (buf) * 16384 + wave * 1024;                        \
    GLOAD_LDS16(arow0 + (ka),  als);                                          \
    GLOAD_LDS16(arow1 + (ka),  als + 512);                                    \
    GLOAD_LDS16(b1row0 + (ka), bls);                                          \
    GLOAD_LDS16(b1row1 + (ka), bls + 512);                                    \
    GLOAD_LDS16(b2row0 + (ka), bls + 8192);                                   \
    GLOAD_LDS16(b2row1 + (ka), bls + 8704); }

#define COMPUTE(buf)                                                          \
  { bf16x8 af[8];                                                             \
    _Pragma("unroll") for (int i = 0; i < 8; i++)                             \
      af[i] = *(const bf16x8*)(&Als[(buf) * 8192 + (miB + i) * 512 + lane * 8]); \
    __builtin_amdgcn_s_setprio(1);                                            \
    _Pragma("unroll") for (int e = 0; e < 2; e++) {                           \
      bf16x8 bfr[4];                                                          \
      _Pragma("unroll") for (int j = 0; j < 4; j++)                           \
        bfr[j] = *(const bf16x8*)(&Bls[(buf) * 16384 + e * 8192 + (niB + j) * 512 + lane * 8]); \
      _Pragma("unroll") for (int i = 0; i < 8; i++)                           \
        _Pragma("unroll") for (int j = 0; j < 4; j++)                         \
          acc[i][j] = __builtin_amdgcn_mfma_f32_16x16x32_bf16(af[i], bfr[j], acc[i][j], 0, 0, 0); } \
    __builtin_amdgcn_s_setprio(0); }

#define WAIT6 asm volatile("s_waitcnt vmcnt(6)" ::: "memory")
#define WAIT0 asm volatile("s_waitcnt vmcnt(0)" ::: "memory")
#define BAR   __builtin_amdgcn_s_barrier()

  // prologue: slices 0,1 (slice s -> buf s%3)
  STAGE(0, 0);
  STAGE(1, 32);
  int ka = 64;   // next slice to stage = slice 2
  // steps t = 0..59, 3x-unrolled for compile-time buffer indices
  for (int tt = 0; tt < 20; ++tt) {
    WAIT6; BAR; STAGE(2, ka); ka += 32; COMPUTE(0);
    WAIT6; BAR; STAGE(0, ka); ka += 32; COMPUTE(1);
    WAIT6; BAR; STAGE(1, ka); ka += 32; COMPUTE(2);
  }
  // t=60: stage slice 62 -> buf2; t=61: stage slice 63 -> buf0
  WAIT6; BAR; STAGE(2, 62 * 32); COMPUTE(0);
  WAIT6; BAR; STAGE(0, 63 * 32); COMPUTE(1);
  // t=62: outstanding slices 62,63 -> vmcnt(6) proves 62 landed
  WAIT6; BAR; COMPUTE(2);
  // t=63: only slice 63 outstanding -> full drain
  WAIT0; BAR; COMPUTE(0);

  // epilogue: C/D layout col=lane&15, row=(lane>>4)*4+reg; one writer per element
  const int wm = (wave >> 2) * 128;
  const int wn = (wave & 3) * 64;
  float bsum[4]; int colv[4];
#pragma unroll
  for (int j = 0; j < 4; j++) {
    colv[j] = n0 + wn + j * 16 + l15;
    bsum[j] = bias[e1 * DM + colv[j]] + bias[e2 * DM + colv[j]];
  }
#pragma unroll
  for (int i = 0; i < 8; i++) {
    int tokr[4];
#pragma unroll
    for (int r = 0; r < 4; r++) {
      const int row = wm + i * 16 + lhi * 4 + r;
      tokr[r] = (row < nrows) ? token_list[tokoff + row] : -1;
    }
#pragma unroll
    for (int j = 0; j < 4; j++)
#pragma unroll
      for (int r = 0; r < 4; r++)
        if (tokr[r] >= 0) out[(size_t)tokr[r] * DM + colv[j]] = acc[i][j][r] + bsum[j];
  }
#undef STAGE
#undef COMPUTE
#undef WAIT6
#undef WAIT0
#undef BAR
}

extern "C" void kernel_launch(void* const* d_in, const int* in_sizes, int n_in,
                              void* d_out, int out_size, void* d_ws, size_t ws_size,
                              hipStream_t stream) {
  const float* hs = (const float*)d_in[0];
  const float* Wg = (const float*)d_in[1];
  const float* bg = (const float*)d_in[2];
  const float* W  = (const float*)d_in[3];
  const float* b  = (const float*)d_in[4];
  float* out = (float*)d_out;

  char* ws = (char*)d_ws;
  int* pair_cnt    = (int*)(ws + 0);      // 64 ints
  int* pair_fill   = (int*)(ws + 256);    // 64 ints
  int* meta        = (int*)(ws + 512);    // 16 ints
  int* pair_off    = (int*)(ws + 576);    // 64 ints
  int* tile_pid    = (int*)(ws + 832);    // MAXT capacity, 96 used
  int* tile_tokoff = (int*)(ws + 1600);   // MAXT
  int* tile_nrows  = (int*)(ws + 2368);   // MAXT
  int* pairs       = (int*)(ws + 3136);   // 16384
  int* token_list  = (int*)(ws + 68672);  // 16384
  ushort_t* Wb  = (ushort_t*)(ws + 134400);              // 64 MiB
  ushort_t* hsb = (ushort_t*)(ws + 134400 + 67108864);   // 64 MiB

  hipMemsetAsync(d_ws, 0, 576, stream);   // pair_cnt + pair_fill + meta

  prep_kernel<<<8192 + 4096, 256, 0, stream>>>(W, Wb, hs, Wg, bg, pair_cnt, pairs, hsb);
  scan_kernel<<<1, 64, 0, stream>>>(pair_cnt, meta, pair_off, tile_pid, tile_tokoff, tile_nrows);
  scatter_kernel<<<NTOK / 256, 256, 0, stream>>>(pairs, pair_off, pair_fill, token_list);
  moe_gemm<<<MAXB * NT, 512, 0, stream>>>(hsb, Wb, b, token_list, meta,
                                          tile_pid, tile_tokoff, tile_nrows, out);
}